// Round 1
// baseline (1318.267 us; speedup 1.0000x reference)
//
#include <hip/hip_runtime.h>
#include <math.h>

#define NHEADS 16
#define HDIM   64
#define BATCH  2
#define SEQLEN 2048
#define DIMSZ  1024
#define BNROWS 4096   // BATCH*SEQLEN

// R[pos][c]: c<32 -> cos(pos*theta_c), c>=32 -> sin(pos*theta_{c-32})
// theta_i = 10000^(-i/32), computed in double then rounded to f32 so the
// f32 product pos*theta matches the reference's f32 freqs bit-for-bit-ish.
__device__ __forceinline__ float rope_theta(int c) {
    int i = c & 31;
    return (float)pow(10000.0, -(double)i / 32.0);
}

// ---------------------------------------------------------------------------
// Projection + bias + rope -> Out in (b, h, n, d) layout.
// Y = X @ W^T + bias ; rope applied per 64-wide head (tile == head).
// ---------------------------------------------------------------------------
__global__ __launch_bounds__(256) void proj_rope_kernel(
    const float* __restrict__ X, const float* __restrict__ W,
    const float* __restrict__ bias, float* __restrict__ Out)
{
    __shared__ float Xs[32][68];   // [k][row]
    __shared__ float Ws[32][68];   // [k][col]
    const int tid = threadIdx.x;
    const int tx = tid & 15, ty = tid >> 4;
    const int row0 = blockIdx.y * 64;
    const int h    = blockIdx.x;          // head == 64-col tile
    const int col0 = h * 64;
    const int lr = tid >> 2;              // 0..63
    const int lc = (tid & 3) * 8;         // 0,8,16,24

    float acc[4][4] = {};
    for (int k0 = 0; k0 < DIMSZ; k0 += 32) {
        float4 xa = *reinterpret_cast<const float4*>(&X[(size_t)(row0 + lr) * DIMSZ + k0 + lc]);
        float4 xb = *reinterpret_cast<const float4*>(&X[(size_t)(row0 + lr) * DIMSZ + k0 + lc + 4]);
        float4 wa = *reinterpret_cast<const float4*>(&W[(size_t)(col0 + lr) * DIMSZ + k0 + lc]);
        float4 wb = *reinterpret_cast<const float4*>(&W[(size_t)(col0 + lr) * DIMSZ + k0 + lc + 4]);
        __syncthreads();
        Xs[lc + 0][lr] = xa.x; Xs[lc + 1][lr] = xa.y; Xs[lc + 2][lr] = xa.z; Xs[lc + 3][lr] = xa.w;
        Xs[lc + 4][lr] = xb.x; Xs[lc + 5][lr] = xb.y; Xs[lc + 6][lr] = xb.z; Xs[lc + 7][lr] = xb.w;
        Ws[lc + 0][lr] = wa.x; Ws[lc + 1][lr] = wa.y; Ws[lc + 2][lr] = wa.z; Ws[lc + 3][lr] = wa.w;
        Ws[lc + 4][lr] = wb.x; Ws[lc + 5][lr] = wb.y; Ws[lc + 6][lr] = wb.z; Ws[lc + 7][lr] = wb.w;
        __syncthreads();
        #pragma unroll
        for (int kk = 0; kk < 32; ++kk) {
            float4 a4 = *reinterpret_cast<const float4*>(&Xs[kk][4 * ty]);
            float4 b4 = *reinterpret_cast<const float4*>(&Ws[kk][4 * tx]);
            float av[4] = {a4.x, a4.y, a4.z, a4.w};
            float bv[4] = {b4.x, b4.y, b4.z, b4.w};
            #pragma unroll
            for (int i = 0; i < 4; ++i)
                #pragma unroll
                for (int j = 0; j < 4; ++j)
                    acc[i][j] += av[i] * bv[j];
        }
    }

    float4 bb = *reinterpret_cast<const float4*>(&bias[col0 + 4 * tx]);
    float bv[4] = {bb.x, bb.y, bb.z, bb.w};
    float th[4];
    #pragma unroll
    for (int j = 0; j < 4; ++j) th[j] = rope_theta(4 * tx + j);
    const bool is_cos = (tx < 8);   // cols 4tx+j < 32 ?

    #pragma unroll
    for (int i = 0; i < 4; ++i) {
        int grow = row0 + 4 * ty + i;
        int b = grow >> 11;
        int n = grow & (SEQLEN - 1);
        float o0 = acc[i][0] + bv[0];
        float o1 = acc[i][1] + bv[1];
        float o2 = acc[i][2] + bv[2];
        float o3 = acc[i][3] + bv[3];
        float fn = (float)n;
        float R0, R1, R2, R3;
        if (is_cos) {
            R0 = cosf(fn * th[0]); R1 = cosf(fn * th[1]);
            R2 = cosf(fn * th[2]); R3 = cosf(fn * th[3]);
        } else {
            R0 = sinf(fn * th[0]); R1 = sinf(fn * th[1]);
            R2 = sinf(fn * th[2]); R3 = sinf(fn * th[3]);
        }
        // pair p = 2tx  : out[p]   = x[4tx]*R0   - x[4tx+1]*R1 ; out[p+32] = x[4tx]*R1 + x[4tx+1]*R0
        // pair p = 2tx+1: out[p]   = x[4tx+2]*R2 - x[4tx+3]*R3 ; out[p+32] = x[4tx+2]*R3 + x[4tx+3]*R2
        float yp0 = o0 * R0 - o1 * R1;
        float yp1 = o2 * R2 - o3 * R3;
        float yq0 = o0 * R1 + o1 * R0;
        float yq1 = o2 * R3 + o3 * R2;
        float* dst = &Out[(((size_t)b * NHEADS + h) * SEQLEN + n) * HDIM];
        *reinterpret_cast<float2*>(&dst[2 * tx])      = make_float2(yp0, yp1);
        *reinterpret_cast<float2*>(&dst[2 * tx + 32]) = make_float2(yq0, yq1);
    }
}

// ---------------------------------------------------------------------------
// Flash attention over (b,h): online softmax, 64-query tile, 64-key tiles.
// Epilogue applies -rope and writes Y in (b, n, dim) layout.
// ---------------------------------------------------------------------------
__global__ __launch_bounds__(256) void attn_kernel(
    const float* __restrict__ Q, const float* __restrict__ K,
    const float* __restrict__ V, float* __restrict__ Y)
{
    __shared__ float Qs[64][68];   // [d][q]
    __shared__ float KP[64][68];   // K phase: [d][k]; P phase: [k][q]
    __shared__ float Vs[64][68];   // [k][d]
    const int tid = threadIdx.x;
    const int tx = tid & 15, ty = tid >> 4;
    const int bh = blockIdx.y;
    const int b  = bh >> 4;
    const int h  = bh & 15;
    const int q0 = blockIdx.x * 64;
    const int lr = tid >> 2;              // 0..63
    const int lc = (tid & 3) * 16;        // 0,16,32,48
    const float* Qb = Q + (size_t)bh * SEQLEN * HDIM;
    const float* Kb = K + (size_t)bh * SEQLEN * HDIM;
    const float* Vb = V + (size_t)bh * SEQLEN * HDIM;

    {   // load Q tile transposed
        float4 t[4];
        #pragma unroll
        for (int u = 0; u < 4; ++u)
            t[u] = *reinterpret_cast<const float4*>(&Qb[(size_t)(q0 + lr) * HDIM + lc + 4 * u]);
        #pragma unroll
        for (int u = 0; u < 4; ++u) {
            Qs[lc + 4 * u + 0][lr] = t[u].x;
            Qs[lc + 4 * u + 1][lr] = t[u].y;
            Qs[lc + 4 * u + 2][lr] = t[u].z;
            Qs[lc + 4 * u + 3][lr] = t[u].w;
        }
    }

    float acc[4][4] = {};
    float mrow[4] = {-INFINITY, -INFINITY, -INFINITY, -INFINITY};
    float lrow[4] = {};

    for (int kt = 0; kt < SEQLEN / 64; ++kt) {
        const int k0 = kt * 64;
        float4 kv[4], vv[4];
        #pragma unroll
        for (int u = 0; u < 4; ++u) {
            kv[u] = *reinterpret_cast<const float4*>(&Kb[(size_t)(k0 + lr) * HDIM + lc + 4 * u]);
            vv[u] = *reinterpret_cast<const float4*>(&Vb[(size_t)(k0 + lr) * HDIM + lc + 4 * u]);
        }
        __syncthreads();   // prev iteration done reading KP/Vs
        #pragma unroll
        for (int u = 0; u < 4; ++u) {
            KP[lc + 4 * u + 0][lr] = kv[u].x;
            KP[lc + 4 * u + 1][lr] = kv[u].y;
            KP[lc + 4 * u + 2][lr] = kv[u].z;
            KP[lc + 4 * u + 3][lr] = kv[u].w;
            *reinterpret_cast<float4*>(&Vs[lr][lc + 4 * u]) = vv[u];
        }
        __syncthreads();

        float s[4][4] = {};
        #pragma unroll
        for (int d = 0; d < 64; ++d) {
            float4 qa = *reinterpret_cast<const float4*>(&Qs[d][4 * ty]);
            float4 kb = *reinterpret_cast<const float4*>(&KP[d][4 * tx]);
            float av[4] = {qa.x, qa.y, qa.z, qa.w};
            float bv2[4] = {kb.x, kb.y, kb.z, kb.w};
            #pragma unroll
            for (int i = 0; i < 4; ++i)
                #pragma unroll
                for (int j = 0; j < 4; ++j)
                    s[i][j] += av[i] * bv2[j];
        }
        float p[4][4];
        float sc[4];
        #pragma unroll
        for (int i = 0; i < 4; ++i) {
            #pragma unroll
            for (int j = 0; j < 4; ++j) s[i][j] *= 0.125f;   // 1/sqrt(64)
            float mx = fmaxf(fmaxf(s[i][0], s[i][1]), fmaxf(s[i][2], s[i][3]));
            #pragma unroll
            for (int m = 1; m < 16; m <<= 1) mx = fmaxf(mx, __shfl_xor(mx, m));
            float mnew = fmaxf(mrow[i], mx);
            sc[i] = expf(mrow[i] - mnew);
            mrow[i] = mnew;
            float sm = 0.f;
            #pragma unroll
            for (int j = 0; j < 4; ++j) { p[i][j] = expf(s[i][j] - mnew); sm += p[i][j]; }
            #pragma unroll
            for (int m = 1; m < 16; m <<= 1) sm += __shfl_xor(sm, m);
            lrow[i] = lrow[i] * sc[i] + sm;
            #pragma unroll
            for (int j = 0; j < 4; ++j) acc[i][j] *= sc[i];
        }
        __syncthreads();   // done reading K from KP
        #pragma unroll
        for (int i = 0; i < 4; ++i)
            #pragma unroll
            for (int j = 0; j < 4; ++j)
                KP[4 * tx + j][4 * ty + i] = p[i][j];   // P^T: [k][q]
        __syncthreads();
        #pragma unroll
        for (int k = 0; k < 64; ++k) {
            float4 pa = *reinterpret_cast<const float4*>(&KP[k][4 * ty]);
            float4 vb4 = *reinterpret_cast<const float4*>(&Vs[k][4 * tx]);
            float av[4] = {pa.x, pa.y, pa.z, pa.w};
            float bv2[4] = {vb4.x, vb4.y, vb4.z, vb4.w};
            #pragma unroll
            for (int i = 0; i < 4; ++i)
                #pragma unroll
                for (int j = 0; j < 4; ++j)
                    acc[i][j] += av[i] * bv2[j];
        }
    }

    // epilogue: /l, apply -rope, write (b, n, dim)
    float th[4];
    #pragma unroll
    for (int j = 0; j < 4; ++j) th[j] = rope_theta(4 * tx + j);
    const bool is_cos = (tx < 8);
    #pragma unroll
    for (int i = 0; i < 4; ++i) {
        float inv = 1.0f / lrow[i];
        float o0 = acc[i][0] * inv;
        float o1 = acc[i][1] * inv;
        float o2 = acc[i][2] * inv;
        float o3 = acc[i][3] * inv;
        int q = q0 + 4 * ty + i;
        float fn = (float)q;
        float R0, R1, R2, R3;
        if (is_cos) {
            R0 = cosf(fn * th[0]); R1 = cosf(fn * th[1]);
            R2 = cosf(fn * th[2]); R3 = cosf(fn * th[3]);
        } else {
            R0 = sinf(fn * th[0]); R1 = sinf(fn * th[1]);
            R2 = sinf(fn * th[2]); R3 = sinf(fn * th[3]);
        }
        float yp0 = -(o0 * R0 - o1 * R1);
        float yp1 = -(o2 * R2 - o3 * R3);
        float yq0 = -(o0 * R1 + o1 * R0);
        float yq1 = -(o2 * R3 + o3 * R2);
        float* dst = &Y[((size_t)b * SEQLEN + q) * DIMSZ + h * HDIM];
        *reinterpret_cast<float2*>(&dst[2 * tx])      = make_float2(yp0, yp1);
        *reinterpret_cast<float2*>(&dst[2 * tx + 32]) = make_float2(yq0, yq1);
    }
}

// ---------------------------------------------------------------------------
// Out = Y @ Wo^T + bo  -> d_out (BNROWS, DIMSZ)
// ---------------------------------------------------------------------------
__global__ __launch_bounds__(256) void gemm_out_kernel(
    const float* __restrict__ X, const float* __restrict__ W,
    const float* __restrict__ bias, float* __restrict__ Out)
{
    __shared__ float Xs[32][68];
    __shared__ float Ws[32][68];
    const int tid = threadIdx.x;
    const int tx = tid & 15, ty = tid >> 4;
    const int row0 = blockIdx.y * 64;
    const int col0 = blockIdx.x * 64;
    const int lr = tid >> 2;
    const int lc = (tid & 3) * 8;

    float acc[4][4] = {};
    for (int k0 = 0; k0 < DIMSZ; k0 += 32) {
        float4 xa = *reinterpret_cast<const float4*>(&X[(size_t)(row0 + lr) * DIMSZ + k0 + lc]);
        float4 xb = *reinterpret_cast<const float4*>(&X[(size_t)(row0 + lr) * DIMSZ + k0 + lc + 4]);
        float4 wa = *reinterpret_cast<const float4*>(&W[(size_t)(col0 + lr) * DIMSZ + k0 + lc]);
        float4 wb = *reinterpret_cast<const float4*>(&W[(size_t)(col0 + lr) * DIMSZ + k0 + lc + 4]);
        __syncthreads();
        Xs[lc + 0][lr] = xa.x; Xs[lc + 1][lr] = xa.y; Xs[lc + 2][lr] = xa.z; Xs[lc + 3][lr] = xa.w;
        Xs[lc + 4][lr] = xb.x; Xs[lc + 5][lr] = xb.y; Xs[lc + 6][lr] = xb.z; Xs[lc + 7][lr] = xb.w;
        Ws[lc + 0][lr] = wa.x; Ws[lc + 1][lr] = wa.y; Ws[lc + 2][lr] = wa.z; Ws[lc + 3][lr] = wa.w;
        Ws[lc + 4][lr] = wb.x; Ws[lc + 5][lr] = wb.y; Ws[lc + 6][lr] = wb.z; Ws[lc + 7][lr] = wb.w;
        __syncthreads();
        #pragma unroll
        for (int kk = 0; kk < 32; ++kk) {
            float4 a4 = *reinterpret_cast<const float4*>(&Xs[kk][4 * ty]);
            float4 b4 = *reinterpret_cast<const float4*>(&Ws[kk][4 * tx]);
            float av[4] = {a4.x, a4.y, a4.z, a4.w};
            float bv[4] = {b4.x, b4.y, b4.z, b4.w};
            #pragma unroll
            for (int i = 0; i < 4; ++i)
                #pragma unroll
                for (int j = 0; j < 4; ++j)
                    acc[i][j] += av[i] * bv[j];
        }
    }

    float4 bb = *reinterpret_cast<const float4*>(&bias[col0 + 4 * tx]);
    #pragma unroll
    for (int i = 0; i < 4; ++i) {
        float4 r;
        r.x = acc[i][0] + bb.x;
        r.y = acc[i][1] + bb.y;
        r.z = acc[i][2] + bb.z;
        r.w = acc[i][3] + bb.w;
        *reinterpret_cast<float4*>(&Out[(size_t)(row0 + 4 * ty + i) * DIMSZ + col0 + 4 * tx]) = r;
    }
}

extern "C" void kernel_launch(void* const* d_in, const int* in_sizes, int n_in,
                              void* d_out, int out_size, void* d_ws, size_t ws_size,
                              hipStream_t stream) {
    const float* x  = (const float*)d_in[0];
    const float* Wq = (const float*)d_in[1];
    const float* bq = (const float*)d_in[2];
    const float* Wk = (const float*)d_in[3];
    const float* bk = (const float*)d_in[4];
    const float* Wv = (const float*)d_in[5];
    const float* bv = (const float*)d_in[6];
    const float* Wo = (const float*)d_in[7];
    const float* bo = (const float*)d_in[8];
    float* out = (float*)d_out;

    const size_t TS = (size_t)BATCH * NHEADS * SEQLEN * HDIM;   // 4,194,304 floats
    float* Qw = (float*)d_ws;
    float* Kw = Qw + TS;
    float* Vw = Kw + TS;
    float* Yw = Vw + TS;

    dim3 blk(256);
    proj_rope_kernel<<<dim3(16, 64), blk, 0, stream>>>(x, Wq, bq, Qw);
    proj_rope_kernel<<<dim3(16, 64), blk, 0, stream>>>(x, Wk, bk, Kw);
    proj_rope_kernel<<<dim3(16, 64), blk, 0, stream>>>(x, Wv, bv, Vw);
    attn_kernel<<<dim3(SEQLEN / 64, BATCH * NHEADS), blk, 0, stream>>>(Qw, Kw, Vw, Yw);
    gemm_out_kernel<<<dim3(16, 64), blk, 0, stream>>>(Yw, Wo, bo, out);
}

// Round 2
// 669.132 us; speedup vs baseline: 1.9701x; 1.9701x over previous
//
#include <hip/hip_runtime.h>
#include <hip/hip_bf16.h>
#include <math.h>

#define NHEADS 16
#define HDIM   64
#define BATCH  2
#define SEQLEN 2048
#define DIMSZ  1024

typedef __bf16 bf16x8 __attribute__((ext_vector_type(8)));
typedef float  f32x4  __attribute__((ext_vector_type(4)));
typedef unsigned short u16x8 __attribute__((ext_vector_type(8)));

__device__ __forceinline__ float rope_theta(int c) {
    int i = c & 31;
    return (float)pow(10000.0, -(double)i / 32.0);
}
__device__ __forceinline__ unsigned short bf16u(float f) {
    __hip_bfloat16 h = __float2bfloat16(f);
    return *reinterpret_cast<unsigned short*>(&h);
}

// ---------------------------------------------------------------------------
// Projection + bias + rope -> bf16 Out in (b, h, n, d) layout.
// ---------------------------------------------------------------------------
__global__ __launch_bounds__(256) void proj_rope_kernel(
    const float* __restrict__ X, const float* __restrict__ W,
    const float* __restrict__ bias, unsigned short* __restrict__ Out)
{
    __shared__ float Xs[32][68];   // [k][row]
    __shared__ float Ws[32][68];   // [k][col]
    const int tid = threadIdx.x;
    const int tx = tid & 15, ty = tid >> 4;
    const int row0 = blockIdx.y * 64;
    const int h    = blockIdx.x;
    const int col0 = h * 64;
    const int lr = tid >> 2;
    const int lc = (tid & 3) * 8;

    float acc[4][4] = {};
    for (int k0 = 0; k0 < DIMSZ; k0 += 32) {
        float4 xa = *reinterpret_cast<const float4*>(&X[(size_t)(row0 + lr) * DIMSZ + k0 + lc]);
        float4 xb = *reinterpret_cast<const float4*>(&X[(size_t)(row0 + lr) * DIMSZ + k0 + lc + 4]);
        float4 wa = *reinterpret_cast<const float4*>(&W[(size_t)(col0 + lr) * DIMSZ + k0 + lc]);
        float4 wb = *reinterpret_cast<const float4*>(&W[(size_t)(col0 + lr) * DIMSZ + k0 + lc + 4]);
        __syncthreads();
        Xs[lc + 0][lr] = xa.x; Xs[lc + 1][lr] = xa.y; Xs[lc + 2][lr] = xa.z; Xs[lc + 3][lr] = xa.w;
        Xs[lc + 4][lr] = xb.x; Xs[lc + 5][lr] = xb.y; Xs[lc + 6][lr] = xb.z; Xs[lc + 7][lr] = xb.w;
        Ws[lc + 0][lr] = wa.x; Ws[lc + 1][lr] = wa.y; Ws[lc + 2][lr] = wa.z; Ws[lc + 3][lr] = wa.w;
        Ws[lc + 4][lr] = wb.x; Ws[lc + 5][lr] = wb.y; Ws[lc + 6][lr] = wb.z; Ws[lc + 7][lr] = wb.w;
        __syncthreads();
        #pragma unroll
        for (int kk = 0; kk < 32; ++kk) {
            float4 a4 = *reinterpret_cast<const float4*>(&Xs[kk][4 * ty]);
            float4 b4 = *reinterpret_cast<const float4*>(&Ws[kk][4 * tx]);
            float av[4] = {a4.x, a4.y, a4.z, a4.w};
            float bv[4] = {b4.x, b4.y, b4.z, b4.w};
            #pragma unroll
            for (int i = 0; i < 4; ++i)
                #pragma unroll
                for (int j = 0; j < 4; ++j)
                    acc[i][j] += av[i] * bv[j];
        }
    }

    float4 bb = *reinterpret_cast<const float4*>(&bias[col0 + 4 * tx]);
    float bv[4] = {bb.x, bb.y, bb.z, bb.w};
    float th[4];
    #pragma unroll
    for (int j = 0; j < 4; ++j) th[j] = rope_theta(4 * tx + j);
    const bool is_cos = (tx < 8);

    #pragma unroll
    for (int i = 0; i < 4; ++i) {
        int grow = row0 + 4 * ty + i;
        int b = grow >> 11;
        int n = grow & (SEQLEN - 1);
        float o0 = acc[i][0] + bv[0];
        float o1 = acc[i][1] + bv[1];
        float o2 = acc[i][2] + bv[2];
        float o3 = acc[i][3] + bv[3];
        float fn = (float)n;
        float R0, R1, R2, R3;
        if (is_cos) {
            R0 = cosf(fn * th[0]); R1 = cosf(fn * th[1]);
            R2 = cosf(fn * th[2]); R3 = cosf(fn * th[3]);
        } else {
            R0 = sinf(fn * th[0]); R1 = sinf(fn * th[1]);
            R2 = sinf(fn * th[2]); R3 = sinf(fn * th[3]);
        }
        float yp0 = o0 * R0 - o1 * R1;
        float yp1 = o2 * R2 - o3 * R3;
        float yq0 = o0 * R1 + o1 * R0;
        float yq1 = o2 * R3 + o3 * R2;
        unsigned short* dst = &Out[(((size_t)b * NHEADS + h) * SEQLEN + n) * HDIM];
        unsigned int lo = (unsigned int)bf16u(yp0) | ((unsigned int)bf16u(yp1) << 16);
        unsigned int hi = (unsigned int)bf16u(yq0) | ((unsigned int)bf16u(yq1) << 16);
        *reinterpret_cast<unsigned int*>(&dst[2 * tx])      = lo;
        *reinterpret_cast<unsigned int*>(&dst[2 * tx + 32]) = hi;
    }
}

// ---------------------------------------------------------------------------
// MFMA flash attention. 4 waves x 16 q-rows, 64-key LDS tiles (XOR-swizzled).
// smem: K [64 rows][128B] @0 ; V^T [64 d][128B] @8192 ; P [wave][16][128B] @16384
// Epilogue: O/l -> LDS (f32, aliases K/V^T) -> -rope -> Y (b,n,dim) f32.
// ---------------------------------------------------------------------------
__global__ __launch_bounds__(256) void attn_mfma_kernel(
    const unsigned short* __restrict__ Q, const unsigned short* __restrict__ K,
    const unsigned short* __restrict__ V, float* __restrict__ Y)
{
    __shared__ __align__(16) unsigned char smem[24576];
    const int tid = threadIdx.x;
    const int w   = tid >> 6;
    const int l   = tid & 63;
    const int g   = l >> 4;
    const int lx  = l & 15;
    const int bh  = blockIdx.y;
    const int b   = bh >> 4;
    const int h   = bh & 15;
    const int q0  = blockIdx.x * 64;

    const unsigned short* Qb = Q + (size_t)bh * SEQLEN * HDIM;
    const unsigned short* Kb = K + (size_t)bh * SEQLEN * HDIM;
    const unsigned short* Vb = V + (size_t)bh * SEQLEN * HDIM;

    // Q A-frags: row = q0 + w*16 + lx, k(d) = g*8..g*8+7 (+32 for chunk 1)
    bf16x8 qf[2];
    {
        const unsigned short* src = Qb + (size_t)(q0 + w * 16 + lx) * HDIM + g * 8;
        qf[0] = *reinterpret_cast<const bf16x8*>(src);
        qf[1] = *reinterpret_cast<const bf16x8*>(src + 32);
    }

    f32x4 oacc[4] = {};
    float mrow[4] = {-1e30f, -1e30f, -1e30f, -1e30f};
    float lrow[4] = {0.f, 0.f, 0.f, 0.f};

    for (int kt = 0; kt < SEQLEN / 64; ++kt) {
        const int k0 = kt * 64;
        __syncthreads();   // prev iteration done reading K/V^T
        // ---- stage K tile, swizzled: byte = key*128 + (colb ^ ((key&7)<<4))
        #pragma unroll
        for (int p = 0; p < 2; ++p) {
            int idx = p * 256 + tid;
            int key = idx >> 3, ch = idx & 7;
            u16x8 v = *reinterpret_cast<const u16x8*>(Kb + (size_t)(k0 + key) * HDIM + ch * 8);
            *reinterpret_cast<u16x8*>(&smem[key * 128 + ((ch * 16) ^ ((key & 7) << 4))]) = v;
        }
        // ---- stage V transposed: VT[d][key], byte = d*128 + ((key*2) ^ ((d&7)<<4))
        {
            int key = tid & 63, dg = tid >> 6;
            const unsigned short* src = Vb + (size_t)(k0 + key) * HDIM + dg * 16;
            u16x8 v0 = *reinterpret_cast<const u16x8*>(src);
            u16x8 v1 = *reinterpret_cast<const u16x8*>(src + 8);
            #pragma unroll
            for (int i = 0; i < 8; ++i) {
                int d0 = dg * 16 + i;
                int d1 = d0 + 8;
                *reinterpret_cast<unsigned short*>(&smem[8192 + d0 * 128 + ((key * 2) ^ ((d0 & 7) << 4))]) = (unsigned short)v0[i];
                *reinterpret_cast<unsigned short*>(&smem[8192 + d1 * 128 + ((key * 2) ^ ((d1 & 7) << 4))]) = (unsigned short)v1[i];
            }
        }
        __syncthreads();

        // ---- QK^T: S[16q x 64key] per wave
        f32x4 sacc[4] = {};
        #pragma unroll
        for (int c = 0; c < 4; ++c) {
            int key = c * 16 + lx;
            int rowb = key * 128, sw = (key & 7) << 4;
            bf16x8 b0 = *reinterpret_cast<const bf16x8*>(&smem[rowb + ((g * 16) ^ sw)]);
            bf16x8 b1 = *reinterpret_cast<const bf16x8*>(&smem[rowb + ((64 + g * 16) ^ sw)]);
            sacc[c] = __builtin_amdgcn_mfma_f32_16x16x32_bf16(qf[0], b0, sacc[c], 0, 0, 0);
            sacc[c] = __builtin_amdgcn_mfma_f32_16x16x32_bf16(qf[1], b1, sacc[c], 0, 0, 0);
        }

        // ---- online softmax on raw logits (scale 0.125 folded into exp)
        #pragma unroll
        for (int r = 0; r < 4; ++r) {
            float mx = fmaxf(fmaxf(sacc[0][r], sacc[1][r]), fmaxf(sacc[2][r], sacc[3][r]));
            #pragma unroll
            for (int mm = 1; mm < 16; mm <<= 1) mx = fmaxf(mx, __shfl_xor(mx, mm));
            float mnew = fmaxf(mrow[r], mx);
            float sc = __expf((mrow[r] - mnew) * 0.125f);
            mrow[r] = mnew;
            float p0 = __expf((sacc[0][r] - mnew) * 0.125f);
            float p1 = __expf((sacc[1][r] - mnew) * 0.125f);
            float p2 = __expf((sacc[2][r] - mnew) * 0.125f);
            float p3 = __expf((sacc[3][r] - mnew) * 0.125f);
            sacc[0][r] = p0; sacc[1][r] = p1; sacc[2][r] = p2; sacc[3][r] = p3;
            float sm = p0 + p1 + p2 + p3;
            #pragma unroll
            for (int mm = 1; mm < 16; mm <<= 1) sm += __shfl_xor(sm, mm);
            lrow[r] = lrow[r] * sc + sm;
            #pragma unroll
            for (int c2 = 0; c2 < 4; ++c2) oacc[c2][r] *= sc;
        }

        // ---- P -> per-wave LDS (bf16, swizzled)
        const int pbase = 16384 + w * 2048;
        #pragma unroll
        for (int c = 0; c < 4; ++c)
            #pragma unroll
            for (int r = 0; r < 4; ++r) {
                int q = g * 4 + r;
                int key = c * 16 + lx;
                *reinterpret_cast<__bf16*>(&smem[pbase + q * 128 + ((key * 2) ^ ((q & 7) << 4))]) = (__bf16)sacc[c][r];
            }
        asm volatile("s_waitcnt lgkmcnt(0)" ::: "memory");

        // ---- PV: O += P @ V
        #pragma unroll
        for (int kc = 0; kc < 2; ++kc) {
            bf16x8 pf = *reinterpret_cast<const bf16x8*>(
                &smem[pbase + lx * 128 + ((kc * 64 + g * 16) ^ ((lx & 7) << 4))]);
            #pragma unroll
            for (int c = 0; c < 4; ++c) {
                int d = c * 16 + lx;
                bf16x8 vf = *reinterpret_cast<const bf16x8*>(
                    &smem[8192 + d * 128 + ((kc * 64 + g * 16) ^ ((d & 7) << 4))]);
                oacc[c] = __builtin_amdgcn_mfma_f32_16x16x32_bf16(pf, vf, oacc[c], 0, 0, 0);
            }
        }
    }

    // ---- epilogue: normalize, stash O in LDS (aliases K/V^T), -rope, store
    __syncthreads();
    float inv[4];
    #pragma unroll
    for (int r = 0; r < 4; ++r) inv[r] = 1.0f / lrow[r];
    float* OS = (float*)smem;   // [64][68]
    #pragma unroll
    for (int c = 0; c < 4; ++c)
        #pragma unroll
        for (int r = 0; r < 4; ++r)
            OS[(w * 16 + g * 4 + r) * 68 + c * 16 + lx] = oacc[c][r] * inv[r];
    __syncthreads();

    const int tx = tid & 15, ty = tid >> 4;
    float th[4];
    #pragma unroll
    for (int j = 0; j < 4; ++j) th[j] = rope_theta(4 * tx + j);
    const bool is_cos = (tx < 8);
    #pragma unroll
    for (int rep = 0; rep < 4; ++rep) {
        int row = ty + rep * 16;
        int q = q0 + row;
        f32x4 o = *reinterpret_cast<const f32x4*>(&OS[row * 68 + 4 * tx]);
        float fn = (float)q;
        float R0, R1, R2, R3;
        if (is_cos) {
            R0 = cosf(fn * th[0]); R1 = cosf(fn * th[1]);
            R2 = cosf(fn * th[2]); R3 = cosf(fn * th[3]);
        } else {
            R0 = sinf(fn * th[0]); R1 = sinf(fn * th[1]);
            R2 = sinf(fn * th[2]); R3 = sinf(fn * th[3]);
        }
        float yp0 = -(o[0] * R0 - o[1] * R1);
        float yp1 = -(o[2] * R2 - o[3] * R3);
        float yq0 = -(o[0] * R1 + o[1] * R0);
        float yq1 = -(o[2] * R3 + o[3] * R2);
        float* dst = &Y[((size_t)b * SEQLEN + q) * DIMSZ + h * HDIM];
        *reinterpret_cast<float2*>(&dst[2 * tx])      = make_float2(yp0, yp1);
        *reinterpret_cast<float2*>(&dst[2 * tx + 32]) = make_float2(yq0, yq1);
    }
}

// ---------------------------------------------------------------------------
// Out = Y @ Wo^T + bo  (f32)
// ---------------------------------------------------------------------------
__global__ __launch_bounds__(256) void gemm_out_kernel(
    const float* __restrict__ X, const float* __restrict__ W,
    const float* __restrict__ bias, float* __restrict__ Out)
{
    __shared__ float Xs[32][68];
    __shared__ float Ws[32][68];
    const int tid = threadIdx.x;
    const int tx = tid & 15, ty = tid >> 4;
    const int row0 = blockIdx.y * 64;
    const int col0 = blockIdx.x * 64;
    const int lr = tid >> 2;
    const int lc = (tid & 3) * 8;

    float acc[4][4] = {};
    for (int k0 = 0; k0 < DIMSZ; k0 += 32) {
        float4 xa = *reinterpret_cast<const float4*>(&X[(size_t)(row0 + lr) * DIMSZ + k0 + lc]);
        float4 xb = *reinterpret_cast<const float4*>(&X[(size_t)(row0 + lr) * DIMSZ + k0 + lc + 4]);
        float4 wa = *reinterpret_cast<const float4*>(&W[(size_t)(col0 + lr) * DIMSZ + k0 + lc]);
        float4 wb = *reinterpret_cast<const float4*>(&W[(size_t)(col0 + lr) * DIMSZ + k0 + lc + 4]);
        __syncthreads();
        Xs[lc + 0][lr] = xa.x; Xs[lc + 1][lr] = xa.y; Xs[lc + 2][lr] = xa.z; Xs[lc + 3][lr] = xa.w;
        Xs[lc + 4][lr] = xb.x; Xs[lc + 5][lr] = xb.y; Xs[lc + 6][lr] = xb.z; Xs[lc + 7][lr] = xb.w;
        Ws[lc + 0][lr] = wa.x; Ws[lc + 1][lr] = wa.y; Ws[lc + 2][lr] = wa.z; Ws[lc + 3][lr] = wa.w;
        Ws[lc + 4][lr] = wb.x; Ws[lc + 5][lr] = wb.y; Ws[lc + 6][lr] = wb.z; Ws[lc + 7][lr] = wb.w;
        __syncthreads();
        #pragma unroll
        for (int kk = 0; kk < 32; ++kk) {
            float4 a4 = *reinterpret_cast<const float4*>(&Xs[kk][4 * ty]);
            float4 b4 = *reinterpret_cast<const float4*>(&Ws[kk][4 * tx]);
            float av[4] = {a4.x, a4.y, a4.z, a4.w};
            float bv[4] = {b4.x, b4.y, b4.z, b4.w};
            #pragma unroll
            for (int i = 0; i < 4; ++i)
                #pragma unroll
                for (int j = 0; j < 4; ++j)
                    acc[i][j] += av[i] * bv[j];
        }
    }

    float4 bb = *reinterpret_cast<const float4*>(&bias[col0 + 4 * tx]);
    #pragma unroll
    for (int i = 0; i < 4; ++i) {
        float4 r;
        r.x = acc[i][0] + bb.x;
        r.y = acc[i][1] + bb.y;
        r.z = acc[i][2] + bb.z;
        r.w = acc[i][3] + bb.w;
        *reinterpret_cast<float4*>(&Out[(size_t)(row0 + 4 * ty + i) * DIMSZ + col0 + 4 * tx]) = r;
    }
}

extern "C" void kernel_launch(void* const* d_in, const int* in_sizes, int n_in,
                              void* d_out, int out_size, void* d_ws, size_t ws_size,
                              hipStream_t stream) {
    const float* x  = (const float*)d_in[0];
    const float* Wq = (const float*)d_in[1];
    const float* bq = (const float*)d_in[2];
    const float* Wk = (const float*)d_in[3];
    const float* bk = (const float*)d_in[4];
    const float* Wv = (const float*)d_in[5];
    const float* bv = (const float*)d_in[6];
    const float* Wo = (const float*)d_in[7];
    const float* bo = (const float*)d_in[8];
    float* out = (float*)d_out;

    const size_t TS = (size_t)BATCH * NHEADS * SEQLEN * HDIM;   // 4,194,304 elems
    unsigned short* Qw = (unsigned short*)d_ws;
    unsigned short* Kw = Qw + TS;
    unsigned short* Vw = Kw + TS;
    float* Yw = (float*)(Vw + TS);

    dim3 blk(256);
    proj_rope_kernel<<<dim3(16, 64), blk, 0, stream>>>(x, Wq, bq, Qw);
    proj_rope_kernel<<<dim3(16, 64), blk, 0, stream>>>(x, Wk, bk, Kw);
    proj_rope_kernel<<<dim3(16, 64), blk, 0, stream>>>(x, Wv, bv, Vw);
    attn_mfma_kernel<<<dim3(SEQLEN / 64, BATCH * NHEADS), blk, 0, stream>>>(Qw, Kw, Vw, Yw);
    gemm_out_kernel<<<dim3(16, 64), blk, 0, stream>>>(Yw, Wo, bo, out);
}

// Round 4
// 219.288 us; speedup vs baseline: 6.0116x; 3.0514x over previous
//
#include <hip/hip_runtime.h>
#include <hip/hip_bf16.h>
#include <math.h>

#define NHEADS 16
#define HDIM   64
#define BATCH  2
#define SEQLEN 2048
#define DIMSZ  1024

typedef _Float16 f16x8 __attribute__((ext_vector_type(8)));
typedef float    f32x4 __attribute__((ext_vector_type(4)));
typedef unsigned short u16x8 __attribute__((ext_vector_type(8)));

__device__ __forceinline__ float rope_theta(int c) {
    int i = c & 31;
    return (float)pow(10000.0, -(double)i / 32.0);
}
__device__ __forceinline__ unsigned short f16u(float f) {
    _Float16 h = (_Float16)f;
    return *reinterpret_cast<unsigned short*>(&h);
}
__device__ __forceinline__ void async_copy16(const void* gsrc, void* lds) {
    __builtin_amdgcn_global_load_lds(
        (const __attribute__((address_space(1))) unsigned int*)gsrc,
        (__attribute__((address_space(3))) unsigned int*)lds, 16, 0, 0);
}

// ---------------------------------------------------------------------------
// prep: f32->f16 conversions (x, Wq|Wk|Wv concat, Wo), bias concat, rope tables
// ---------------------------------------------------------------------------
__global__ __launch_bounds__(256) void prep_kernel(
    const float* __restrict__ x, const float* __restrict__ Wq,
    const float* __restrict__ Wk, const float* __restrict__ Wv,
    const float* __restrict__ Wo, const float* __restrict__ bq,
    const float* __restrict__ bk, const float* __restrict__ bv,
    unsigned short* __restrict__ x16, unsigned short* __restrict__ Wqkv16,
    unsigned short* __restrict__ Wo16, float* __restrict__ biasqkv,
    float* __restrict__ ropeC, float* __restrict__ ropeS)
{
    const int NV = (4194304 + 4 * 1048576) / 8;   // 1,048,576 vec8 chunks
    int gid = blockIdx.x * 256 + threadIdx.x;
    for (int i = gid; i < NV; i += gridDim.x * 256) {
        long e = (long)i * 8;
        const float* src; unsigned short* dst; long off;
        if (e < 4194304)      { src = x;  dst = x16;              off = e; }
        else if (e < 5242880) { src = Wq; dst = Wqkv16;           off = e - 4194304; }
        else if (e < 6291456) { src = Wk; dst = Wqkv16 + 1048576; off = e - 5242880; }
        else if (e < 7340032) { src = Wv; dst = Wqkv16 + 2097152; off = e - 6291456; }
        else                  { src = Wo; dst = Wo16;             off = e - 7340032; }
        float4 v0 = *reinterpret_cast<const float4*>(src + off);
        float4 v1 = *reinterpret_cast<const float4*>(src + off + 4);
        u16x8 o;
        o[0] = f16u(v0.x); o[1] = f16u(v0.y); o[2] = f16u(v0.z); o[3] = f16u(v0.w);
        o[4] = f16u(v1.x); o[5] = f16u(v1.y); o[6] = f16u(v1.z); o[7] = f16u(v1.w);
        *reinterpret_cast<u16x8*>(dst + off) = o;
    }
    if (gid < 65536) {
        int npos = gid >> 5, j = gid & 31;
        float f = (float)npos * rope_theta(j);
        ropeC[gid] = cosf(f);
        ropeS[gid] = sinf(f);
    }
    if (gid < 3072) {
        biasqkv[gid] = gid < 1024 ? bq[gid] : (gid < 2048 ? bk[gid - 1024] : bv[gid - 2048]);
    }
}

// ---------------------------------------------------------------------------
// Fused QKV GEMM: C[4096 x 3072] = x16 @ Wqkv16^T + bias, epilogue rope,
// writes f16 QKV[p][b][h][n][d].
// NOTE the reference's apply_rope is non-standard: coefficients for pair p
// are rope[2p], rope[2p+1] where rope = [cos(th_0..31) | sin(th_0..31)] —
// i.e. two cosines (p<16) or two sines (p>=16) of ADJACENT thetas.
//   out[p]    = x[2p]*rope[2p]   - x[2p+1]*rope[2p+1]
//   out[p+32] = x[2p]*rope[2p+1] + x[2p+1]*rope[2p]
// ---------------------------------------------------------------------------
__global__ __launch_bounds__(256) void qkv_gemm_kernel(
    const unsigned short* __restrict__ A, const unsigned short* __restrict__ B,
    const float* __restrict__ bias, const float* __restrict__ ropeC,
    const float* __restrict__ ropeS, unsigned short* __restrict__ QKV)
{
    __shared__ __align__(16) _Float16 As[128][64];
    __shared__ __align__(16) _Float16 Bs[128][64];
    const int tid = threadIdx.x;
    const int w = tid >> 6, lane = tid & 63;
    const int g = lane >> 4, lx = lane & 15;
    const int wr = w >> 1, wc = w & 1;
    const int row0 = blockIdx.y * 128;
    const int col0 = blockIdx.x * 128;
    const unsigned short* Ab = A + (size_t)row0 * DIMSZ;
    const unsigned short* Bb = B + (size_t)col0 * DIMSZ;

    f32x4 acc[4][4] = {};
    for (int k0 = 0; k0 < DIMSZ; k0 += 64) {
        __syncthreads();
        #pragma unroll
        for (int i = 0; i < 4; ++i) {
            int idx = i * 256 + tid;
            int r = idx >> 3, cb = (idx & 7) * 8;
            async_copy16(Ab + (size_t)r * DIMSZ + k0 + cb,
                         (_Float16*)As + (size_t)(i * 256 + w * 64) * 8);
        }
        #pragma unroll
        for (int i = 0; i < 4; ++i) {
            int idx = i * 256 + tid;
            int r = idx >> 3, cb = (idx & 7) * 8;
            async_copy16(Bb + (size_t)r * DIMSZ + k0 + cb,
                         (_Float16*)Bs + (size_t)(i * 256 + w * 64) * 8);
        }
        __syncthreads();
        #pragma unroll
        for (int ks = 0; ks < 2; ++ks) {
            f16x8 af[4], bf[4];
            #pragma unroll
            for (int m = 0; m < 4; ++m)
                af[m] = *reinterpret_cast<const f16x8*>(&As[wr * 64 + m * 16 + lx][ks * 32 + g * 8]);
            #pragma unroll
            for (int n = 0; n < 4; ++n)
                bf[n] = *reinterpret_cast<const f16x8*>(&Bs[wc * 64 + n * 16 + lx][ks * 32 + g * 8]);
            #pragma unroll
            for (int m = 0; m < 4; ++m)
                #pragma unroll
                for (int n = 0; n < 4; ++n)
                    acc[m][n] = __builtin_amdgcn_mfma_f32_16x16x32_f16(af[m], bf[n], acc[m][n], 0, 0, 0);
        }
    }

    // epilogue: bias + (non-standard) rope -> QKV (p,b,h,n,d) f16
    const int hcol0 = col0 + wc * 64;          // multiple of 64, one head
    const int proj  = hcol0 >> 10;
    const int hd    = (hcol0 & 1023) >> 6;
    float bsv[4];
    #pragma unroll
    for (int n = 0; n < 4; ++n) bsv[n] = bias[hcol0 + n * 16 + lx];

    #pragma unroll
    for (int m = 0; m < 4; ++m) {
        int rbase = row0 + wr * 64 + m * 16 + g * 4;
        #pragma unroll
        for (int r2 = 0; r2 < 4; ++r2) {
            int rglob = rbase + r2;
            int b = rglob >> 11, npos = rglob & (SEQLEN - 1);
            const float* rcp = ropeC + npos * 32;
            const float* rsp = ropeS + npos * 32;
            unsigned short* Orow = QKV +
                ((((size_t)proj * BATCH + b) * NHEADS + hd) * SEQLEN + npos) * HDIM;
            #pragma unroll
            for (int n = 0; n < 4; ++n) {
                float v = acc[m][n][r2] + bsv[n];   // x[d], d = n*16+lx
                float o = __shfl_xor(v, 1);         // x[d^1]
                int d = n * 16 + lx;
                const float* tab = (d < 32) ? rcp : rsp;
                float Rd = tab[d & 31];             // rope[d]
                float Rp = tab[(d & 31) ^ 1];       // rope[d^1]
                float y;
                int outc;
                if (d & 1) { y = o * Rd + v * Rp; outc = (d >> 1) + 32; }
                else       { y = v * Rd - o * Rp; outc = d >> 1; }
                Orow[outc] = f16u(y);
            }
        }
    }
}

// ---------------------------------------------------------------------------
// MFMA flash attention (f16). 4 waves x 16 q-rows, 64-key swizzled LDS tiles.
// Epilogue: -rope via tables, writes f16 Y (b,n,dim).
// ---------------------------------------------------------------------------
__global__ __launch_bounds__(256) void attn_mfma_kernel(
    const unsigned short* __restrict__ QKV, const float* __restrict__ ropeC,
    const float* __restrict__ ropeS, unsigned short* __restrict__ Y)
{
    __shared__ __align__(16) unsigned char smem[24576];
    const int tid = threadIdx.x;
    const int w   = tid >> 6;
    const int l   = tid & 63;
    const int g   = l >> 4;
    const int lx  = l & 15;
    const int bh  = blockIdx.y;
    const int b   = bh >> 4;
    const int h   = bh & 15;
    const int q0  = blockIdx.x * 64;

    const unsigned short* Qb = QKV + (size_t)bh * SEQLEN * HDIM;
    const unsigned short* Kb = QKV + 4194304 + (size_t)bh * SEQLEN * HDIM;
    const unsigned short* Vb = QKV + 8388608 + (size_t)bh * SEQLEN * HDIM;

    f16x8 qf[2];
    {
        const unsigned short* src = Qb + (size_t)(q0 + w * 16 + lx) * HDIM + g * 8;
        qf[0] = *reinterpret_cast<const f16x8*>(src);
        qf[1] = *reinterpret_cast<const f16x8*>(src + 32);
    }

    f32x4 oacc[4] = {};
    float mrow[4] = {-1e30f, -1e30f, -1e30f, -1e30f};
    float lrow[4] = {0.f, 0.f, 0.f, 0.f};

    for (int kt = 0; kt < SEQLEN / 64; ++kt) {
        const int k0 = kt * 64;
        __syncthreads();
        #pragma unroll
        for (int p = 0; p < 2; ++p) {
            int idx = p * 256 + tid;
            int key = idx >> 3, ch = idx & 7;
            u16x8 v = *reinterpret_cast<const u16x8*>(Kb + (size_t)(k0 + key) * HDIM + ch * 8);
            *reinterpret_cast<u16x8*>(&smem[key * 128 + ((ch * 16) ^ ((key & 7) << 4))]) = v;
        }
        {
            int key = tid & 63, dg = tid >> 6;
            const unsigned short* src = Vb + (size_t)(k0 + key) * HDIM + dg * 16;
            u16x8 v0 = *reinterpret_cast<const u16x8*>(src);
            u16x8 v1 = *reinterpret_cast<const u16x8*>(src + 8);
            #pragma unroll
            for (int i = 0; i < 8; ++i) {
                int d0 = dg * 16 + i;
                int d1 = d0 + 8;
                *reinterpret_cast<unsigned short*>(&smem[8192 + d0 * 128 + ((key * 2) ^ ((d0 & 7) << 4))]) = (unsigned short)v0[i];
                *reinterpret_cast<unsigned short*>(&smem[8192 + d1 * 128 + ((key * 2) ^ ((d1 & 7) << 4))]) = (unsigned short)v1[i];
            }
        }
        __syncthreads();

        f32x4 sacc[4] = {};
        #pragma unroll
        for (int c = 0; c < 4; ++c) {
            int key = c * 16 + lx;
            int rowb = key * 128, sw = (key & 7) << 4;
            f16x8 b0 = *reinterpret_cast<const f16x8*>(&smem[rowb + ((g * 16) ^ sw)]);
            f16x8 b1 = *reinterpret_cast<const f16x8*>(&smem[rowb + ((64 + g * 16) ^ sw)]);
            sacc[c] = __builtin_amdgcn_mfma_f32_16x16x32_f16(qf[0], b0, sacc[c], 0, 0, 0);
            sacc[c] = __builtin_amdgcn_mfma_f32_16x16x32_f16(qf[1], b1, sacc[c], 0, 0, 0);
        }

        #pragma unroll
        for (int r = 0; r < 4; ++r) {
            float mx = fmaxf(fmaxf(sacc[0][r], sacc[1][r]), fmaxf(sacc[2][r], sacc[3][r]));
            #pragma unroll
            for (int mm = 1; mm < 16; mm <<= 1) mx = fmaxf(mx, __shfl_xor(mx, mm));
            float mnew = fmaxf(mrow[r], mx);
            float sc = __expf((mrow[r] - mnew) * 0.125f);
            mrow[r] = mnew;
            float p0 = __expf((sacc[0][r] - mnew) * 0.125f);
            float p1 = __expf((sacc[1][r] - mnew) * 0.125f);
            float p2 = __expf((sacc[2][r] - mnew) * 0.125f);
            float p3 = __expf((sacc[3][r] - mnew) * 0.125f);
            sacc[0][r] = p0; sacc[1][r] = p1; sacc[2][r] = p2; sacc[3][r] = p3;
            float sm = p0 + p1 + p2 + p3;
            #pragma unroll
            for (int mm = 1; mm < 16; mm <<= 1) sm += __shfl_xor(sm, mm);
            lrow[r] = lrow[r] * sc + sm;
            #pragma unroll
            for (int c2 = 0; c2 < 4; ++c2) oacc[c2][r] *= sc;
        }

        const int pbase = 16384 + w * 2048;
        #pragma unroll
        for (int c = 0; c < 4; ++c)
            #pragma unroll
            for (int r = 0; r < 4; ++r) {
                int q = g * 4 + r;
                int key = c * 16 + lx;
                *reinterpret_cast<_Float16*>(&smem[pbase + q * 128 + ((key * 2) ^ ((q & 7) << 4))]) = (_Float16)sacc[c][r];
            }
        asm volatile("s_waitcnt lgkmcnt(0)" ::: "memory");
        __builtin_amdgcn_sched_barrier(0);

        #pragma unroll
        for (int kc = 0; kc < 2; ++kc) {
            f16x8 pf = *reinterpret_cast<const f16x8*>(
                &smem[pbase + lx * 128 + ((kc * 64 + g * 16) ^ ((lx & 7) << 4))]);
            #pragma unroll
            for (int c = 0; c < 4; ++c) {
                int d = c * 16 + lx;
                f16x8 vf = *reinterpret_cast<const f16x8*>(
                    &smem[8192 + d * 128 + ((kc * 64 + g * 16) ^ ((d & 7) << 4))]);
                oacc[c] = __builtin_amdgcn_mfma_f32_16x16x32_f16(pf, vf, oacc[c], 0, 0, 0);
            }
        }
    }

    __syncthreads();
    float inv[4];
    #pragma unroll
    for (int r = 0; r < 4; ++r) inv[r] = 1.0f / lrow[r];
    float* OS = (float*)smem;   // [64][68]
    #pragma unroll
    for (int c = 0; c < 4; ++c)
        #pragma unroll
        for (int r = 0; r < 4; ++r)
            OS[(w * 16 + g * 4 + r) * 68 + c * 16 + lx] = oacc[c][r] * inv[r];
    __syncthreads();

    const int tx = tid & 15, ty = tid >> 4;
    const bool is_cos = (tx < 8);
    const int ji = (4 * tx) & 31;
    #pragma unroll
    for (int rep = 0; rep < 4; ++rep) {
        int row = ty + rep * 16;
        int q = q0 + row;
        f32x4 o = *reinterpret_cast<const f32x4*>(&OS[row * 68 + 4 * tx]);
        const float* tab = is_cos ? ropeC : ropeS;
        float4 R = *reinterpret_cast<const float4*>(&tab[q * 32 + ji]);
        float yp0 = -(o[0] * R.x - o[1] * R.y);
        float yp1 = -(o[2] * R.z - o[3] * R.w);
        float yq0 = -(o[0] * R.y + o[1] * R.x);
        float yq1 = -(o[2] * R.w + o[3] * R.z);
        unsigned short* dst = &Y[((size_t)b * SEQLEN + q) * DIMSZ + h * HDIM];
        unsigned lo = (unsigned)f16u(yp0) | ((unsigned)f16u(yp1) << 16);
        unsigned hi = (unsigned)f16u(yq0) | ((unsigned)f16u(yq1) << 16);
        *reinterpret_cast<unsigned*>(&dst[2 * tx])      = lo;
        *reinterpret_cast<unsigned*>(&dst[2 * tx + 32]) = hi;
    }
}

// ---------------------------------------------------------------------------
// Out GEMM: out[4096 x 1024] = Y16 @ Wo16^T + bo (f32 out)
// ---------------------------------------------------------------------------
__global__ __launch_bounds__(256) void out_gemm_kernel(
    const unsigned short* __restrict__ A, const unsigned short* __restrict__ B,
    const float* __restrict__ bias, float* __restrict__ Out)
{
    __shared__ __align__(16) _Float16 As[128][64];
    __shared__ __align__(16) _Float16 Bs[128][64];
    const int tid = threadIdx.x;
    const int w = tid >> 6, lane = tid & 63;
    const int g = lane >> 4, lx = lane & 15;
    const int wr = w >> 1, wc = w & 1;
    const int row0 = blockIdx.y * 128;
    const int col0 = blockIdx.x * 128;
    const unsigned short* Ab = A + (size_t)row0 * DIMSZ;
    const unsigned short* Bb = B + (size_t)col0 * DIMSZ;

    f32x4 acc[4][4] = {};
    for (int k0 = 0; k0 < DIMSZ; k0 += 64) {
        __syncthreads();
        #pragma unroll
        for (int i = 0; i < 4; ++i) {
            int idx = i * 256 + tid;
            int r = idx >> 3, cb = (idx & 7) * 8;
            async_copy16(Ab + (size_t)r * DIMSZ + k0 + cb,
                         (_Float16*)As + (size_t)(i * 256 + w * 64) * 8);
        }
        #pragma unroll
        for (int i = 0; i < 4; ++i) {
            int idx = i * 256 + tid;
            int r = idx >> 3, cb = (idx & 7) * 8;
            async_copy16(Bb + (size_t)r * DIMSZ + k0 + cb,
                         (_Float16*)Bs + (size_t)(i * 256 + w * 64) * 8);
        }
        __syncthreads();
        #pragma unroll
        for (int ks = 0; ks < 2; ++ks) {
            f16x8 af[4], bf[4];
            #pragma unroll
            for (int m = 0; m < 4; ++m)
                af[m] = *reinterpret_cast<const f16x8*>(&As[wr * 64 + m * 16 + lx][ks * 32 + g * 8]);
            #pragma unroll
            for (int n = 0; n < 4; ++n)
                bf[n] = *reinterpret_cast<const f16x8*>(&Bs[wc * 64 + n * 16 + lx][ks * 32 + g * 8]);
            #pragma unroll
            for (int m = 0; m < 4; ++m)
                #pragma unroll
                for (int n = 0; n < 4; ++n)
                    acc[m][n] = __builtin_amdgcn_mfma_f32_16x16x32_f16(af[m], bf[n], acc[m][n], 0, 0, 0);
        }
    }

    const int cb0 = col0 + wc * 64;
    float bsv[4];
    #pragma unroll
    for (int n = 0; n < 4; ++n) bsv[n] = bias[cb0 + n * 16 + lx];
    #pragma unroll
    for (int m = 0; m < 4; ++m) {
        int rbase = row0 + wr * 64 + m * 16 + g * 4;
        #pragma unroll
        for (int r2 = 0; r2 < 4; ++r2) {
            float* orow = Out + (size_t)(rbase + r2) * DIMSZ + cb0;
            #pragma unroll
            for (int n = 0; n < 4; ++n)
                orow[n * 16 + lx] = acc[m][n][r2] + bsv[n];
        }
    }
}

extern "C" void kernel_launch(void* const* d_in, const int* in_sizes, int n_in,
                              void* d_out, int out_size, void* d_ws, size_t ws_size,
                              hipStream_t stream) {
    const float* x  = (const float*)d_in[0];
    const float* Wq = (const float*)d_in[1];
    const float* bq = (const float*)d_in[2];
    const float* Wk = (const float*)d_in[3];
    const float* bk = (const float*)d_in[4];
    const float* Wv = (const float*)d_in[5];
    const float* bv = (const float*)d_in[6];
    const float* Wo = (const float*)d_in[7];
    const float* bo = (const float*)d_in[8];
    float* out = (float*)d_out;

    char* ws = (char*)d_ws;
    unsigned short* x16    = (unsigned short*)(ws);
    unsigned short* Wqkv16 = (unsigned short*)(ws + 8388608);
    unsigned short* Wo16   = (unsigned short*)(ws + 14680064);
    float* biasqkv         = (float*)(ws + 16777216);
    float* ropeC           = (float*)(ws + 16793600);
    float* ropeS           = (float*)(ws + 17055744);
    unsigned short* QKVw   = (unsigned short*)(ws + 17825792);
    unsigned short* Yw     = (unsigned short*)(ws + 42991616);

    dim3 blk(256);
    prep_kernel<<<dim3(2048), blk, 0, stream>>>(x, Wq, Wk, Wv, Wo, bq, bk, bv,
                                                x16, Wqkv16, Wo16, biasqkv, ropeC, ropeS);
    qkv_gemm_kernel<<<dim3(24, 32), blk, 0, stream>>>(x16, Wqkv16, biasqkv, ropeC, ropeS, QKVw);
    attn_mfma_kernel<<<dim3(SEQLEN / 64, BATCH * NHEADS), blk, 0, stream>>>(QKVw, ropeC, ropeS, Yw);
    out_gemm_kernel<<<dim3(8, 32), blk, 0, stream>>>(Yw, Wo16, bo, out);
}